// Round 6
// baseline (626.265 us; speedup 1.0000x reference)
//
#include <hip/hip_runtime.h>
#include <math.h>

typedef short v8s __attribute__((ext_vector_type(8)));
typedef float v4f __attribute__((ext_vector_type(4)));

#define NVOX 64000      // 40^3
#define NPAD 74088      // 42^3
#define P2   1764       // 42^2
#define GSTR 592704     // NPAD*8

__device__ __forceinline__ unsigned short bf16rne(float f){
  unsigned int u = __float_as_uint(f);
  u += 0x7FFFu + ((u >> 16) & 1u);
  return (unsigned short)(u >> 16);
}

// ---------------- projection: xp = proj_w @ x ; fp32 [c][n] and bf16 padded [g][p][8c]
__global__ __launch_bounds__(256) void proj_k(const float* __restrict__ x,
                                              const float* __restrict__ pw,
                                              float* __restrict__ xp,
                                              short* __restrict__ xpt){
  int tid = threadIdx.x;
  int m = (blockIdx.x >> 1) * 256 + tid;
  int half = blockIdx.x & 1;
  float xv[64];
#pragma unroll
  for (int i = 0; i < 64; i++) xv[i] = x[(size_t)i * NVOX + m];
  int d = m / 1600; int r = m - d * 1600; int h = r / 40; int w = r - h * 40;
  int p = ((d + 1) * 42 + (h + 1)) * 42 + (w + 1);
  const float4* pw4 = (const float4*)pw;
  for (int g8 = half * 4; g8 < half * 4 + 4; g8++){
    v8s pk;
#pragma unroll
    for (int j = 0; j < 8; j++){
      int co = g8 * 8 + j;
      float acc = 0.f;
#pragma unroll
      for (int q = 0; q < 16; q++){
        float4 pv = pw4[co * 16 + q];   // wave-uniform -> scalar K$ loads
        acc = fmaf(pv.x, xv[4*q+0], acc);
        acc = fmaf(pv.y, xv[4*q+1], acc);
        acc = fmaf(pv.z, xv[4*q+2], acc);
        acc = fmaf(pv.w, xv[4*q+3], acc);
      }
      xp[(size_t)co * NVOX + m] = acc;
      pk[j] = (short)bf16rne(acc);
    }
    *(v8s*)(xpt + (size_t)g8 * GSTR + (size_t)p * 8) = pk;
  }
}

// ---------------- fused w+h box passes per (c,d) slice (zero pad)
__global__ __launch_bounds__(256) void boxwh_k(const float* __restrict__ in,
                                               float* __restrict__ out){
  __shared__ float s0[1600], s1[1600];
  size_t base = (size_t)blockIdx.x * 1600;
  int t = threadIdx.x;
  for (int e = t; e < 1600; e += 256) s0[e] = in[base + e];
  __syncthreads();
  for (int e = t; e < 1600; e += 256){
    int w = e % 40;
    float s = s0[e];
    if (w > 0)  s += s0[e - 1];
    if (w < 39) s += s0[e + 1];
    s1[e] = s;
  }
  __syncthreads();
  for (int e = t; e < 1600; e += 256){
    int h = e / 40;
    float s = s1[e];
    if (h > 0)  s += s1[e - 40];
    if (h < 39) s += s1[e + 40];
    out[base + e] = s;
  }
}
__global__ void boxd_k(const float* __restrict__ in, float* __restrict__ out){
  int g = blockIdx.x * 256 + threadIdx.x;
  int d = (g / 1600) % 40;
  float s = in[g];
  if (d > 0)  s += in[g - 1600];
  if (d < 39) s += in[g + 1600];
  out[g] = s * (1.f / 27.f);
}

// ---------------- kmeans init
__global__ void kinit_k(const float* __restrict__ xm, float* __restrict__ km){
  int t = threadIdx.x;
  km[t] = xm[(size_t)(t & 63) * NVOX + (t >> 6)];
  if (t < 4) km[256 + t] = 1.f;
  for (int j = 260 + t; j < 12 * 260; j += 256) km[j] = 0.f;
}

// ---------------- kmeans assign: 4 lanes/point (lane q = 16 channels).
// 64 points/block, 1000 blocks, 4000 waves. Shuffle-reduce dots; wave-local
// LDS transpose for the centroid-sum reduction (no same-address atomics).
__global__ __launch_bounds__(256) void assign_k(const float* __restrict__ xm,
                                                const float* __restrict__ kin,
                                                float* __restrict__ kout,
                                                int* __restrict__ idx, int mode){
  __shared__ float s_cent[256];
  __shared__ float s_cc[4];
  __shared__ float s_red[260];
  __shared__ float s_x[4][16][68];
  __shared__ int   s_kb[64];
  int t = threadIdx.x, lane = t & 63, wv = t >> 6;
  int q = lane & 3, p = lane >> 2;
  s_cent[t] = kin[t] / fmaxf(kin[256 + (t >> 6)], 1.f);
  if (t < 4) s_red[256 + t] = 0.f;
  if (t < 4){
    // cc after cent is loaded: defer via sync below
  }
  for (int j = t; j < 256; j += 256) s_red[j] = 0.f;
  __syncthreads();
  if (t < 4){
    const float4* cc4 = (const float4*)(s_cent + t * 64);
    float s = 0.f;
#pragma unroll
    for (int e = 0; e < 16; e++){
      float4 v = cc4[e];
      s = fmaf(v.x, v.x, s); s = fmaf(v.y, v.y, s);
      s = fmaf(v.z, v.z, s); s = fmaf(v.w, v.w, s);
    }
    s_cc[t] = s;
  }
  __syncthreads();
  int n = blockIdx.x * 64 + wv * 16 + p;
  // 16 channels of this lane: c = q*16 + j
  float4 x4[4];
#pragma unroll
  for (int j4 = 0; j4 < 4; j4++){
    float4 v;
    v.x = xm[(size_t)(q * 16 + j4 * 4 + 0) * NVOX + n];
    v.y = xm[(size_t)(q * 16 + j4 * 4 + 1) * NVOX + n];
    v.z = xm[(size_t)(q * 16 + j4 * 4 + 2) * NVOX + n];
    v.w = xm[(size_t)(q * 16 + j4 * 4 + 3) * NVOX + n];
    x4[j4] = v;
  }
  const float4* c4 = (const float4*)s_cent;
  float dk[4];
#pragma unroll
  for (int k = 0; k < 4; k++){
    float s = 0.f;
#pragma unroll
    for (int j4 = 0; j4 < 4; j4++){
      float4 cv = c4[k * 16 + q * 4 + j4];
      s = fmaf(cv.x, x4[j4].x, s); s = fmaf(cv.y, x4[j4].y, s);
      s = fmaf(cv.z, x4[j4].z, s); s = fmaf(cv.w, x4[j4].w, s);
    }
    dk[k] = s;
  }
#pragma unroll
  for (int k = 0; k < 4; k++){
    dk[k] += __shfl_xor(dk[k], 1, 64);
    dk[k] += __shfl_xor(dk[k], 2, 64);
  }
  float sc0 = s_cc[0] - 2.f * dk[0];
  float sc1 = s_cc[1] - 2.f * dk[1];
  float sc2 = s_cc[2] - 2.f * dk[2];
  float sc3 = s_cc[3] - 2.f * dk[3];
  int kb = 0; float bs = sc0;
  if (sc1 < bs){ bs = sc1; kb = 1; }
  if (sc2 < bs){ bs = sc2; kb = 2; }
  if (sc3 < bs){ bs = sc3; kb = 3; }
  if (mode){
    if (q == 0) idx[n] = kb;
  } else {
    if (q == 0) s_kb[wv * 16 + p] = kb;
    // wave-local transpose: store my 16 channels of point p
#pragma unroll
    for (int j4 = 0; j4 < 4; j4++)
      *(float4*)(&s_x[wv][p][q * 16 + j4 * 4]) = x4[j4];
    // lane = channel: sum this wave's 16 points (DS is in-order per wave)
    float a0 = 0.f, a1 = 0.f, a2 = 0.f, a3 = 0.f;
#pragma unroll
    for (int pp = 0; pp < 16; pp++){
      float v = s_x[wv][pp][lane];
      int kj = s_kb[wv * 16 + pp];
      a0 += (kj == 0) ? v : 0.f;
      a1 += (kj == 1) ? v : 0.f;
      a2 += (kj == 2) ? v : 0.f;
      a3 += (kj == 3) ? v : 0.f;
    }
    atomicAdd(&s_red[lane], a0);
    atomicAdd(&s_red[64 + lane], a1);
    atomicAdd(&s_red[128 + lane], a2);
    atomicAdd(&s_red[192 + lane], a3);
#pragma unroll
    for (int kk = 0; kk < 4; kk++){
      unsigned long long m = __ballot(q == 0 && kb == kk);
      if (lane == 0) atomicAdd(&s_red[256 + kk], (float)__popcll(m));
    }
    __syncthreads();
    for (int j = t; j < 260; j += 256) atomicAdd(&kout[j], s_red[j]);
  }
}

// ---------------- gating MLPs (1 block, 256 thr)
__global__ void mlp_k(const float* __restrict__ km10,
                      const float* __restrict__ w1, const float* __restrict__ b1,
                      const float* __restrict__ w2, const float* __restrict__ b2,
                      const float* __restrict__ w3, const float* __restrict__ b3,
                      const float* __restrict__ u1, const float* __restrict__ c1,
                      const float* __restrict__ u2, const float* __restrict__ c2,
                      const float* __restrict__ u3, const float* __restrict__ c3,
                      float* __restrict__ wi, float* __restrict__ bias){
  __shared__ float s_feat[256], s_h1[128], s_h2[128], s_g1[64], s_g2[64];
  int t = threadIdx.x;
  s_feat[t] = km10[t] / fmaxf(km10[256 + (t >> 6)], 1.f);
  __syncthreads();
  if (t < 128){
    float z = b1[t];
    for (int i = 0; i < 256; i++) z = fmaf(s_feat[i], w1[i * 128 + t], z);
    s_h1[t] = fmaxf(z, 0.f);
  }
  __syncthreads();
  if (t < 128){
    float z = b2[t];
    for (int i = 0; i < 128; i++) z = fmaf(s_h1[i], w2[i * 128 + t], z);
    s_h2[t] = fmaxf(z, 0.f);
  }
  __syncthreads();
  if (t < 108){
    float z = b3[t];
    for (int i = 0; i < 128; i++) z = fmaf(s_h2[i], w3[i * 108 + t], z);
    wi[t] = 1.f / (1.f + expf(-z));
  }
  if (t < 64){
    float z = c1[t];
    for (int i = 0; i < 256; i++) z = fmaf(s_feat[i], u1[i * 64 + t], z);
    s_g1[t] = fmaxf(z, 0.f);
  }
  __syncthreads();
  if (t < 64){
    float z = c2[t];
    for (int i = 0; i < 64; i++) z = fmaf(s_g1[i], u2[i * 64 + t], z);
    s_g2[t] = fmaxf(z, 0.f);
  }
  __syncthreads();
  {
    float z = c3[t];
    for (int i = 0; i < 64; i++) z = fmaf(s_g2[i], u3[i * 256 + t], z);
    bias[t] = z;
  }
}

// ---------------- base_w fp32 (o,c,t) -> bf16 [t][o][c]
__global__ void bwprep_k(const float* __restrict__ bw, short* __restrict__ bwb){
  int e = blockIdx.x * 256 + threadIdx.x;           // 0 .. 110591
  int t = e >> 12; int rem = e & 4095;
  int o = rem >> 6; int c = rem & 63;
  bwb[e] = (short)bf16rne(bw[(o * 64 + c) * 27 + t]);
}

// ---------------- main dynamic conv: 32-voxel tile, 4 independent waves
// (mh-split over output channels), full K per wave, no LDS reduce.
__global__ __launch_bounds__(256) void conv_k(const short* __restrict__ xpt,
                                              const short* __restrict__ bwb,
                                              const float* __restrict__ wi,
                                              const float* __restrict__ bias,
                                              const int* __restrict__ idx,
                                              const float* __restrict__ x,
                                              const float* __restrict__ pa,
                                              float* __restrict__ out){
  static const int POFF[27] = {
    -P2-42-1, -P2-42, -P2-42+1, -P2-1, -P2, -P2+1, -P2+42-1, -P2+42, -P2+42+1,
    -42-1, -42, -42+1, -1, 0, 1, 42-1, 42, 42+1,
    P2-42-1, P2-42, P2-42+1, P2-1, P2, P2+1, P2+42-1, P2+42, P2+42+1 };
  __shared__ float s_wi[108];
  __shared__ float s_bias[256];
  int tid = threadIdx.x;
  for (int j = tid; j < 108; j += 256) s_wi[j] = wi[j];
  s_bias[tid] = bias[tid];
  __syncthreads();
  int mh = tid >> 6, lane = tid & 63;
  int col = lane & 15, kg = lane >> 4;
  int vb = blockIdx.x * 32;
  int ki2[2], p2[2];
#pragma unroll
  for (int nt = 0; nt < 2; nt++){
    int v = vb + nt * 16 + col;
    ki2[nt] = idx[v];
    int d = v / 1600; int r = v - d * 1600; int h = r / 40; int w = r - h * 40;
    p2[nt] = ((d + 1) * 42 + (h + 1)) * 42 + (w + 1);
  }
  const short* bg0 = xpt + (size_t)kg * GSTR;         // kc=0 plane group
  const short* bg1 = xpt + (size_t)(4 + kg) * GSTR;   // kc=1
  const short* bp00 = bg0 + (size_t)p2[0] * 8;
  const short* bp01 = bg1 + (size_t)p2[0] * 8;
  const short* bp10 = bg0 + (size_t)p2[1] * 8;
  const short* bp11 = bg1 + (size_t)p2[1] * 8;
  int ao = (mh * 16 + col) * 64 + kg * 8;             // kc=1 at +32
  v4f acc0 = {0.f, 0.f, 0.f, 0.f};
  v4f acc1 = {0.f, 0.f, 0.f, 0.f};
  v4f zero = {0.f, 0.f, 0.f, 0.f};
#pragma unroll 9
  for (int t = 0; t < 27; t++){
    int po8 = POFF[t] * 8;
    const short* at = bwb + t * 4096 + ao;
    v8s a0 = *(const v8s*)(at);
    v8s a1 = *(const v8s*)(at + 32);
    v8s b00 = *(const v8s*)(bp00 + po8);
    v8s b01 = *(const v8s*)(bp01 + po8);
    v8s b10 = *(const v8s*)(bp10 + po8);
    v8s b11 = *(const v8s*)(bp11 + po8);
    float wk0 = s_wi[ki2[0] * 27 + t];
    float wk1 = s_wi[ki2[1] * 27 + t];
    v4f tp = __builtin_amdgcn_mfma_f32_16x16x32_bf16(a0, b00, zero, 0, 0, 0);
    tp = __builtin_amdgcn_mfma_f32_16x16x32_bf16(a1, b01, tp, 0, 0, 0);
    acc0 += tp * wk0;
    v4f tq = __builtin_amdgcn_mfma_f32_16x16x32_bf16(a0, b10, zero, 0, 0, 0);
    tq = __builtin_amdgcn_mfma_f32_16x16x32_bf16(a1, b11, tq, 0, 0, 0);
    acc1 += tq * wk1;
  }
  float pav = pa[0];
#pragma unroll
  for (int nt = 0; nt < 2; nt++){
    v4f a = (nt == 0) ? acc0 : acc1;
    int n = vb + nt * 16 + col;
    int kb = ki2[nt];
#pragma unroll
    for (int r = 0; r < 4; r++){
      int o = mh * 16 + kg * 4 + r;
      float val = a[r] + s_bias[kb * 64 + o];
      val = (val >= 0.f) ? val : pav * val;
      size_t off = (size_t)o * NVOX + n;
      out[off] = val + x[off];
    }
  }
}

extern "C" void kernel_launch(void* const* d_in, const int* in_sizes, int n_in,
                              void* d_out, int out_size, void* d_ws, size_t ws_size,
                              hipStream_t stream){
  const float* x    = (const float*)d_in[0];
  const float* pw   = (const float*)d_in[1];
  const float* bw   = (const float*)d_in[2];
  const float* gkw1 = (const float*)d_in[3];
  const float* gkb1 = (const float*)d_in[4];
  const float* gkw2 = (const float*)d_in[5];
  const float* gkb2 = (const float*)d_in[6];
  const float* gkw3 = (const float*)d_in[7];
  const float* gkb3 = (const float*)d_in[8];
  const float* gbw1 = (const float*)d_in[9];
  const float* gbb1 = (const float*)d_in[10];
  const float* gbw2 = (const float*)d_in[11];
  const float* gbb2 = (const float*)d_in[12];
  const float* gbw3 = (const float*)d_in[13];
  const float* gbb3 = (const float*)d_in[14];
  const float* pa   = (const float*)d_in[15];
  float* outp = (float*)d_out;

  float* ws   = (float*)d_ws;
  float* XP   = ws;                                  // 4,096,000 f
  float* BU2  = ws + 4096000;                        // 4,096,000 f
  float* BU1  = ws + 8192000;                        // 4,096,000 f (xm)
  short* XPT  = (short*)(ws + 12288000);             // 4,741,632 s
  short* BWB  = XPT + (size_t)NPAD * 64;             // 110,592 s
  float* KM   = (float*)(BWB + 110592);              // 3120 f
  float* WI   = KM + 3120;                           // 108 f
  float* BIAS = WI + 108;                            // 256 f
  int*   IDX  = (int*)(BIAS + 256);                  // 64,000 i

  hipMemsetAsync(XPT, 0, (size_t)NPAD * 64 * 2, stream);
  proj_k<<<500, 256, 0, stream>>>(x, pw, XP, XPT);
  boxwh_k<<<2560, 256, 0, stream>>>(XP, BU2);
  boxd_k<<<16000, 256, 0, stream>>>(BU2, BU1);
  kinit_k<<<1, 256, 0, stream>>>(BU1, KM);
  for (int i = 0; i <= 10; i++)
    assign_k<<<1000, 256, 0, stream>>>(BU1, KM + i * 260, KM + (i + 1) * 260, IDX,
                                       (i == 10) ? 1 : 0);
  mlp_k<<<1, 256, 0, stream>>>(KM + 10 * 260,
                               gkw1, gkb1, gkw2, gkb2, gkw3, gkb3,
                               gbw1, gbb1, gbw2, gbb2, gbw3, gbb3,
                               WI, BIAS);
  bwprep_k<<<432, 256, 0, stream>>>(bw, BWB);
  conv_k<<<2000, 256, 0, stream>>>(XPT, BWB, WI, BIAS, IDX, x, pa, outp);
}

// Round 10
// 451.826 us; speedup vs baseline: 1.3861x; 1.3861x over previous
//
#include <hip/hip_runtime.h>
#include <math.h>

typedef short v8s __attribute__((ext_vector_type(8)));
typedef float v4f __attribute__((ext_vector_type(4)));

#define NVOX 64000      // 40^3
#define NPAD 74088      // 42^3
#define P2   1764       // 42^2
#define GSTR 592704     // NPAD*8

__device__ __forceinline__ unsigned short bf16rne(float f){
  unsigned int u = __float_as_uint(f);
  u += 0x7FFFu + ((u >> 16) & 1u);
  return (unsigned short)(u >> 16);
}

// ---------------- projection: xp = proj_w @ x ; fp32 [c][n] and bf16 padded [g][p][8c]
__global__ __launch_bounds__(256) void proj_k(const float* __restrict__ x,
                                              const float* __restrict__ pw,
                                              float* __restrict__ xp,
                                              short* __restrict__ xpt){
  int tid = threadIdx.x;
  int m = (blockIdx.x >> 1) * 256 + tid;
  int half = blockIdx.x & 1;
  float xv[64];
#pragma unroll
  for (int i = 0; i < 64; i++) xv[i] = x[(size_t)i * NVOX + m];
  int d = m / 1600; int r = m - d * 1600; int h = r / 40; int w = r - h * 40;
  int p = ((d + 1) * 42 + (h + 1)) * 42 + (w + 1);
  const float4* pw4 = (const float4*)pw;
  for (int g8 = half * 4; g8 < half * 4 + 4; g8++){
    v8s pk;
#pragma unroll
    for (int j = 0; j < 8; j++){
      int co = g8 * 8 + j;
      float acc = 0.f;
#pragma unroll
      for (int q = 0; q < 16; q++){
        float4 pv = pw4[co * 16 + q];   // wave-uniform -> scalar K$ loads
        acc = fmaf(pv.x, xv[4*q+0], acc);
        acc = fmaf(pv.y, xv[4*q+1], acc);
        acc = fmaf(pv.z, xv[4*q+2], acc);
        acc = fmaf(pv.w, xv[4*q+3], acc);
      }
      xp[(size_t)co * NVOX + m] = acc;
      pk[j] = (short)bf16rne(acc);
    }
    *(v8s*)(xpt + (size_t)g8 * GSTR + (size_t)p * 8) = pk;
  }
}

// ---------------- fused w+h box passes per (c,d) slice (zero pad)
__global__ __launch_bounds__(256) void boxwh_k(const float* __restrict__ in,
                                               float* __restrict__ out){
  __shared__ float s0[1600], s1[1600];
  size_t base = (size_t)blockIdx.x * 1600;
  int t = threadIdx.x;
  for (int e = t; e < 1600; e += 256) s0[e] = in[base + e];
  __syncthreads();
  for (int e = t; e < 1600; e += 256){
    int w = e % 40;
    float s = s0[e];
    if (w > 0)  s += s0[e - 1];
    if (w < 39) s += s0[e + 1];
    s1[e] = s;
  }
  __syncthreads();
  for (int e = t; e < 1600; e += 256){
    int h = e / 40;
    float s = s1[e];
    if (h > 0)  s += s1[e - 40];
    if (h < 39) s += s1[e + 40];
    out[base + e] = s;
  }
}
__global__ void boxd_k(const float* __restrict__ in, float* __restrict__ out){
  int g = blockIdx.x * 256 + threadIdx.x;
  int d = (g / 1600) % 40;
  float s = in[g];
  if (d > 0)  s += in[g - 1600];
  if (d < 39) s += in[g + 1600];
  out[g] = s * (1.f / 27.f);
}

// ---------------- transpose xm [c][n] -> xmt [n][c] (LDS 64x64 tiles)
__global__ __launch_bounds__(256) void transp_k(const float* __restrict__ in,
                                                float* __restrict__ out){
  __shared__ float tile[64][65];
  int t = threadIdx.x;
  int nb = blockIdx.x * 64;
  int l = t & 63, g = t >> 6;
  for (int cc = g; cc < 64; cc += 4)
    tile[cc][l] = in[(size_t)cc * NVOX + nb + l];       // coalesced read
  __syncthreads();
  for (int nn = g; nn < 64; nn += 4)
    out[(size_t)(nb + nn) * 64 + l] = tile[l][nn];      // coalesced write
}

// ---------------- kmeans init (from transposed layout)
__global__ void kinit_k(const float* __restrict__ xmt, float* __restrict__ km){
  int t = threadIdx.x;
  km[t] = xmt[(size_t)(t >> 6) * 64 + (t & 63)];
  if (t < 4) km[256 + t] = 1.f;
  for (int j = 260 + t; j < 12 * 260; j += 256) km[j] = 0.f;
}

// ---------------- kmeans assign + reduce (mode 0) or idx write (mode 1)
// R5-verbatim math; loads switched to 16x float4 from transposed [n][c].
__global__ __launch_bounds__(128) void assign_k(const float* __restrict__ xmt,
                                                const float* __restrict__ kin,
                                                float* __restrict__ kout,
                                                int* __restrict__ idx, int mode){
  __shared__ float s_cent[256];
  __shared__ float s_cc[4];
  __shared__ float s_red[260];
  __shared__ float s_x[128 * 65];
  __shared__ int   s_kb[128];
  int t = threadIdx.x, lane = t & 63, wv = t >> 6;
  for (int j = t; j < 256; j += 128) s_cent[j] = kin[j] / fmaxf(kin[256 + (j >> 6)], 1.f);
  for (int j = t; j < 260; j += 128) s_red[j] = 0.f;
  __syncthreads();
  if (t < 4){
    const float4* cc4 = (const float4*)(s_cent + t * 64);
    float s = 0.f;
#pragma unroll
    for (int q = 0; q < 16; q++){
      float4 v = cc4[q];
      s = fmaf(v.x, v.x, s); s = fmaf(v.y, v.y, s);
      s = fmaf(v.z, v.z, s); s = fmaf(v.w, v.w, s);
    }
    s_cc[t] = s;
  }
  __syncthreads();
  int n = blockIdx.x * 128 + t;
  const float4* xt = (const float4*)(xmt + (size_t)n * 64);
  float4 xq[16];
#pragma unroll
  for (int q = 0; q < 16; q++) xq[q] = xt[q];           // 16 contiguous loads
  float d0 = 0.f, d1 = 0.f, d2 = 0.f, d3 = 0.f;
  const float4* c4 = (const float4*)s_cent;
#pragma unroll
  for (int q = 0; q < 16; q++){
    float4 p0 = c4[q], p1 = c4[16 + q], p2 = c4[32 + q], p3 = c4[48 + q];
    d0 = fmaf(p0.x, xq[q].x, d0); d0 = fmaf(p0.y, xq[q].y, d0);
    d0 = fmaf(p0.z, xq[q].z, d0); d0 = fmaf(p0.w, xq[q].w, d0);
    d1 = fmaf(p1.x, xq[q].x, d1); d1 = fmaf(p1.y, xq[q].y, d1);
    d1 = fmaf(p1.z, xq[q].z, d1); d1 = fmaf(p1.w, xq[q].w, d1);
    d2 = fmaf(p2.x, xq[q].x, d2); d2 = fmaf(p2.y, xq[q].y, d2);
    d2 = fmaf(p2.z, xq[q].z, d2); d2 = fmaf(p2.w, xq[q].w, d2);
    d3 = fmaf(p3.x, xq[q].x, d3); d3 = fmaf(p3.y, xq[q].y, d3);
    d3 = fmaf(p3.z, xq[q].z, d3); d3 = fmaf(p3.w, xq[q].w, d3);
  }
  float sc0 = s_cc[0] - 2.f * d0;
  float sc1 = s_cc[1] - 2.f * d1;
  float sc2 = s_cc[2] - 2.f * d2;
  float sc3 = s_cc[3] - 2.f * d3;
  int kb = 0; float bs = sc0;
  if (sc1 < bs){ bs = sc1; kb = 1; }
  if (sc2 < bs){ bs = sc2; kb = 2; }
  if (sc3 < bs){ bs = sc3; kb = 3; }
  if (mode){
    idx[n] = kb;
  } else {
    s_kb[t] = kb;
#pragma unroll
    for (int q = 0; q < 16; q++){
      s_x[t * 65 + 4*q + 0] = xq[q].x;
      s_x[t * 65 + 4*q + 1] = xq[q].y;
      s_x[t * 65 + 4*q + 2] = xq[q].z;
      s_x[t * 65 + 4*q + 3] = xq[q].w;
    }
    __syncthreads();
    float a0 = 0.f, a1 = 0.f, a2 = 0.f, a3 = 0.f;
    int rowbase = wv * 64;
#pragma unroll 16
    for (int j = 0; j < 64; j++){
      float v = s_x[(rowbase + j) * 65 + lane];          // conflict-free columns
      int kj = s_kb[rowbase + j];                        // broadcast
      a0 += (kj == 0) ? v : 0.f;
      a1 += (kj == 1) ? v : 0.f;
      a2 += (kj == 2) ? v : 0.f;
      a3 += (kj == 3) ? v : 0.f;
    }
    atomicAdd(&s_red[lane], a0);
    atomicAdd(&s_red[64 + lane], a1);
    atomicAdd(&s_red[128 + lane], a2);
    atomicAdd(&s_red[192 + lane], a3);
#pragma unroll
    for (int kk = 0; kk < 4; kk++){
      unsigned long long m = __ballot(kb == kk);
      if (lane == 0) atomicAdd(&s_red[256 + kk], (float)__popcll(m));
    }
    __syncthreads();
    for (int j = t; j < 260; j += 128) atomicAdd(&kout[j], s_red[j]);
  }
}

// ---------------- gating MLPs (1 block, 256 thr)
__global__ void mlp_k(const float* __restrict__ km10,
                      const float* __restrict__ w1, const float* __restrict__ b1,
                      const float* __restrict__ w2, const float* __restrict__ b2,
                      const float* __restrict__ w3, const float* __restrict__ b3,
                      const float* __restrict__ u1, const float* __restrict__ c1,
                      const float* __restrict__ u2, const float* __restrict__ c2,
                      const float* __restrict__ u3, const float* __restrict__ c3,
                      float* __restrict__ wi, float* __restrict__ bias){
  __shared__ float s_feat[256], s_h1[128], s_h2[128], s_g1[64], s_g2[64];
  int t = threadIdx.x;
  s_feat[t] = km10[t] / fmaxf(km10[256 + (t >> 6)], 1.f);
  __syncthreads();
  if (t < 128){
    float z = b1[t];
    for (int i = 0; i < 256; i++) z = fmaf(s_feat[i], w1[i * 128 + t], z);
    s_h1[t] = fmaxf(z, 0.f);
  }
  __syncthreads();
  if (t < 128){
    float z = b2[t];
    for (int i = 0; i < 128; i++) z = fmaf(s_h1[i], w2[i * 128 + t], z);
    s_h2[t] = fmaxf(z, 0.f);
  }
  __syncthreads();
  if (t < 108){
    float z = b3[t];
    for (int i = 0; i < 128; i++) z = fmaf(s_h2[i], w3[i * 108 + t], z);
    wi[t] = 1.f / (1.f + expf(-z));
  }
  if (t < 64){
    float z = c1[t];
    for (int i = 0; i < 256; i++) z = fmaf(s_feat[i], u1[i * 64 + t], z);
    s_g1[t] = fmaxf(z, 0.f);
  }
  __syncthreads();
  if (t < 64){
    float z = c2[t];
    for (int i = 0; i < 64; i++) z = fmaf(s_g1[i], u2[i * 64 + t], z);
    s_g2[t] = fmaxf(z, 0.f);
  }
  __syncthreads();
  {
    float z = c3[t];
    for (int i = 0; i < 64; i++) z = fmaf(s_g2[i], u3[i * 256 + t], z);
    bias[t] = z;
  }
}

// ---------------- base_w fp32 (o,c,t) -> bf16 [t][o][c]
__global__ void bwprep_k(const float* __restrict__ bw, short* __restrict__ bwb){
  int e = blockIdx.x * 256 + threadIdx.x;           // 0 .. 110591
  int t = e >> 12; int rem = e & 4095;
  int o = rem >> 6; int c = rem & 63;
  bwb[e] = (short)bf16rne(bw[(o * 64 + c) * 27 + t]);
}

// ---------------- main dynamic conv (R5-verbatim): 4 waves = 2 mh x 2 kc,
// K-split + LDS reduce. Passed at R5 (49 us).
__global__ __launch_bounds__(256) void conv_k(const short* __restrict__ xpt,
                                              const short* __restrict__ bwb,
                                              const float* __restrict__ wi,
                                              const float* __restrict__ bias,
                                              const int* __restrict__ idx,
                                              const float* __restrict__ x,
                                              const float* __restrict__ pa,
                                              float* __restrict__ out){
  static const int POFF[27] = {
    -P2-42-1, -P2-42, -P2-42+1, -P2-1, -P2, -P2+1, -P2+42-1, -P2+42, -P2+42+1,
    -42-1, -42, -42+1, -1, 0, 1, 42-1, 42, 42+1,
    P2-42-1, P2-42, P2-42+1, P2-1, P2, P2+1, P2+42-1, P2+42, P2+42+1 };
  __shared__ float s_wi[108];
  __shared__ float s_bias[256];
  __shared__ float s_acc[64 * 68];
  int tid = threadIdx.x;
  for (int j = tid; j < 108; j += 256) s_wi[j] = wi[j];
  s_bias[tid] = bias[tid];
  __syncthreads();
  int wv = tid >> 6, lane = tid & 63;
  int kc = wv & 1, mh = wv >> 1;
  int col = lane & 15, kg = lane >> 4;
  int vb = blockIdx.x * 64;
  int p4[4], ki4[4];
#pragma unroll
  for (int nt = 0; nt < 4; nt++){
    int v = vb + nt * 16 + col;
    ki4[nt] = idx[v];
    int d = v / 1600; int r = v - d * 1600; int h = r / 40; int w = r - h * 40;
    p4[nt] = ((d + 1) * 42 + (h + 1)) * 42 + (w + 1);
  }
  const short* bg = xpt + (size_t)(kc * 4 + kg) * GSTR;
  const short* bp0 = bg + (size_t)p4[0] * 8;
  const short* bp1 = bg + (size_t)p4[1] * 8;
  const short* bp2 = bg + (size_t)p4[2] * 8;
  const short* bp3 = bg + (size_t)p4[3] * 8;
  int ao0 = (mh * 32 + col) * 64 + kc * 32 + kg * 8;
  int ao1 = ao0 + 16 * 64;
  v4f acc[2][4];
#pragma unroll
  for (int m2 = 0; m2 < 2; m2++)
#pragma unroll
    for (int nt = 0; nt < 4; nt++) acc[m2][nt] = (v4f){0.f, 0.f, 0.f, 0.f};
  v4f zero = {0.f, 0.f, 0.f, 0.f};
#pragma unroll 9
  for (int t = 0; t < 27; t++){
    int po8 = POFF[t] * 8;
    v8s a0 = *(const v8s*)(bwb + t * 4096 + ao0);
    v8s a1 = *(const v8s*)(bwb + t * 4096 + ao1);
    v8s b0 = *(const v8s*)(bp0 + po8);
    v8s b1 = *(const v8s*)(bp1 + po8);
    v8s b2 = *(const v8s*)(bp2 + po8);
    v8s b3 = *(const v8s*)(bp3 + po8);
    float wk0 = s_wi[ki4[0] * 27 + t];
    float wk1 = s_wi[ki4[1] * 27 + t];
    float wk2 = s_wi[ki4[2] * 27 + t];
    float wk3 = s_wi[ki4[3] * 27 + t];
    v4f tp;
    tp = __builtin_amdgcn_mfma_f32_16x16x32_bf16(a0, b0, zero, 0, 0, 0); acc[0][0] += tp * wk0;
    tp = __builtin_amdgcn_mfma_f32_16x16x32_bf16(a1, b0, zero, 0, 0, 0); acc[1][0] += tp * wk0;
    tp = __builtin_amdgcn_mfma_f32_16x16x32_bf16(a0, b1, zero, 0, 0, 0); acc[0][1] += tp * wk1;
    tp = __builtin_amdgcn_mfma_f32_16x16x32_bf16(a1, b1, zero, 0, 0, 0); acc[1][1] += tp * wk1;
    tp = __builtin_amdgcn_mfma_f32_16x16x32_bf16(a0, b2, zero, 0, 0, 0); acc[0][2] += tp * wk2;
    tp = __builtin_amdgcn_mfma_f32_16x16x32_bf16(a1, b2, zero, 0, 0, 0); acc[1][2] += tp * wk2;
    tp = __builtin_amdgcn_mfma_f32_16x16x32_bf16(a0, b3, zero, 0, 0, 0); acc[0][3] += tp * wk3;
    tp = __builtin_amdgcn_mfma_f32_16x16x32_bf16(a1, b3, zero, 0, 0, 0); acc[1][3] += tp * wk3;
  }
  __syncthreads();
  if (kc == 1){
#pragma unroll
    for (int m2 = 0; m2 < 2; m2++)
#pragma unroll
      for (int nt = 0; nt < 4; nt++)
        *(v4f*)(&s_acc[(nt * 16 + col) * 68 + mh * 32 + m2 * 16 + kg * 4]) = acc[m2][nt];
  }
  __syncthreads();
  if (kc == 0){
    float pav = pa[0];
#pragma unroll
    for (int m2 = 0; m2 < 2; m2++){
#pragma unroll
      for (int nt = 0; nt < 4; nt++){
        v4f other = *(const v4f*)(&s_acc[(nt * 16 + col) * 68 + mh * 32 + m2 * 16 + kg * 4]);
        v4f sum = acc[m2][nt] + other;
        int n = vb + nt * 16 + col;
#pragma unroll
        for (int r = 0; r < 4; r++){
          int o = mh * 32 + m2 * 16 + kg * 4 + r;
          float val = sum[r] + s_bias[ki4[nt] * 64 + o];
          val = (val >= 0.f) ? val : pav * val;
          size_t off = (size_t)o * NVOX + n;
          out[off] = val + x[off];
        }
      }
    }
  }
}

extern "C" void kernel_launch(void* const* d_in, const int* in_sizes, int n_in,
                              void* d_out, int out_size, void* d_ws, size_t ws_size,
                              hipStream_t stream){
  const float* x    = (const float*)d_in[0];
  const float* pw   = (const float*)d_in[1];
  const float* bw   = (const float*)d_in[2];
  const float* gkw1 = (const float*)d_in[3];
  const float* gkb1 = (const float*)d_in[4];
  const float* gkw2 = (const float*)d_in[5];
  const float* gkb2 = (const float*)d_in[6];
  const float* gkw3 = (const float*)d_in[7];
  const float* gkb3 = (const float*)d_in[8];
  const float* gbw1 = (const float*)d_in[9];
  const float* gbb1 = (const float*)d_in[10];
  const float* gbw2 = (const float*)d_in[11];
  const float* gbb2 = (const float*)d_in[12];
  const float* gbw3 = (const float*)d_in[13];
  const float* gbb3 = (const float*)d_in[14];
  const float* pa   = (const float*)d_in[15];
  float* outp = (float*)d_out;

  float* ws   = (float*)d_ws;
  float* XP   = ws;                                  // 4,096,000 f ; reused as XMT
  float* BU2  = ws + 4096000;                        // 4,096,000 f
  float* BU1  = ws + 8192000;                        // 4,096,000 f (xm [c][n])
  short* XPT  = (short*)(ws + 12288000);             // 4,741,632 s
  short* BWB  = XPT + (size_t)NPAD * 64;             // 110,592 s
  float* KM   = (float*)(BWB + 110592);              // 3120 f
  float* WI   = KM + 3120;                           // 108 f
  float* BIAS = WI + 108;                            // 256 f
  int*   IDX  = (int*)(BIAS + 256);                  // 64,000 i
  float* XMT  = XP;                                  // xm transposed [n][c]

  hipMemsetAsync(XPT, 0, (size_t)NPAD * 64 * 2, stream);
  proj_k<<<500, 256, 0, stream>>>(x, pw, XP, XPT);
  boxwh_k<<<2560, 256, 0, stream>>>(XP, BU2);
  boxd_k<<<16000, 256, 0, stream>>>(BU2, BU1);
  transp_k<<<1000, 256, 0, stream>>>(BU1, XMT);
  kinit_k<<<1, 256, 0, stream>>>(XMT, KM);
  for (int i = 0; i <= 10; i++)
    assign_k<<<500, 128, 0, stream>>>(XMT, KM + i * 260, KM + (i + 1) * 260, IDX,
                                      (i == 10) ? 1 : 0);
  mlp_k<<<1, 256, 0, stream>>>(KM + 10 * 260,
                               gkw1, gkb1, gkw2, gkb2, gkw3, gkb3,
                               gbw1, gbb1, gbw2, gbb2, gbw3, gbb3,
                               WI, BIAS);
  bwprep_k<<<432, 256, 0, stream>>>(bw, BWB);
  conv_k<<<1000, 256, 0, stream>>>(XPT, BWB, WI, BIAS, IDX, x, pa, outp);
}

// Round 11
// 332.145 us; speedup vs baseline: 1.8855x; 1.3603x over previous
//
#include <hip/hip_runtime.h>
#include <math.h>

typedef short v8s __attribute__((ext_vector_type(8)));
typedef float v4f __attribute__((ext_vector_type(4)));

#define NVOX 64000      // 40^3
#define NPAD 74088      // 42^3
#define P2   1764       // 42^2
#define GSTR 592704     // NPAD*8
#define NCPY 8          // banked global-accumulator copies
#define ITST (NCPY*260) // stride per kmeans iteration (2080 floats)

__device__ __forceinline__ unsigned short bf16rne(float f){
  unsigned int u = __float_as_uint(f);
  u += 0x7FFFu + ((u >> 16) & 1u);
  return (unsigned short)(u >> 16);
}

// ---------------- projection: xp = proj_w @ x ; fp32 [c][n] and bf16 padded [g][p][8c]
__global__ __launch_bounds__(256) void proj_k(const float* __restrict__ x,
                                              const float* __restrict__ pw,
                                              float* __restrict__ xp,
                                              short* __restrict__ xpt){
  int tid = threadIdx.x;
  int m = (blockIdx.x >> 1) * 256 + tid;
  int half = blockIdx.x & 1;
  float xv[64];
#pragma unroll
  for (int i = 0; i < 64; i++) xv[i] = x[(size_t)i * NVOX + m];
  int d = m / 1600; int r = m - d * 1600; int h = r / 40; int w = r - h * 40;
  int p = ((d + 1) * 42 + (h + 1)) * 42 + (w + 1);
  const float4* pw4 = (const float4*)pw;
  for (int g8 = half * 4; g8 < half * 4 + 4; g8++){
    v8s pk;
#pragma unroll
    for (int j = 0; j < 8; j++){
      int co = g8 * 8 + j;
      float acc = 0.f;
#pragma unroll
      for (int q = 0; q < 16; q++){
        float4 pv = pw4[co * 16 + q];   // wave-uniform -> scalar K$ loads
        acc = fmaf(pv.x, xv[4*q+0], acc);
        acc = fmaf(pv.y, xv[4*q+1], acc);
        acc = fmaf(pv.z, xv[4*q+2], acc);
        acc = fmaf(pv.w, xv[4*q+3], acc);
      }
      xp[(size_t)co * NVOX + m] = acc;
      pk[j] = (short)bf16rne(acc);
    }
    *(v8s*)(xpt + (size_t)g8 * GSTR + (size_t)p * 8) = pk;
  }
}

// ---------------- fused w+h box passes per (c,d) slice (zero pad)
__global__ __launch_bounds__(256) void boxwh_k(const float* __restrict__ in,
                                               float* __restrict__ out){
  __shared__ float s0[1600], s1[1600];
  size_t base = (size_t)blockIdx.x * 1600;
  int t = threadIdx.x;
  for (int e = t; e < 1600; e += 256) s0[e] = in[base + e];
  __syncthreads();
  for (int e = t; e < 1600; e += 256){
    int w = e % 40;
    float s = s0[e];
    if (w > 0)  s += s0[e - 1];
    if (w < 39) s += s0[e + 1];
    s1[e] = s;
  }
  __syncthreads();
  for (int e = t; e < 1600; e += 256){
    int h = e / 40;
    float s = s1[e];
    if (h > 0)  s += s1[e - 40];
    if (h < 39) s += s1[e + 40];
    out[base + e] = s;
  }
}
__global__ void boxd_k(const float* __restrict__ in, float* __restrict__ out){
  int g = blockIdx.x * 256 + threadIdx.x;
  int d = (g / 1600) % 40;
  float s = in[g];
  if (d > 0)  s += in[g - 1600];
  if (d < 39) s += in[g + 1600];
  out[g] = s * (1.f / 27.f);
}

// ---------------- transpose xm [c][n] -> xmt [n][c] (LDS 64x64 tiles)
__global__ __launch_bounds__(256) void transp_k(const float* __restrict__ in,
                                                float* __restrict__ out){
  __shared__ float tile[64][65];
  int t = threadIdx.x;
  int nb = blockIdx.x * 64;
  int l = t & 63, g = t >> 6;
  for (int cc = g; cc < 64; cc += 4)
    tile[cc][l] = in[(size_t)cc * NVOX + nb + l];
  __syncthreads();
  for (int nn = g; nn < 64; nn += 4)
    out[(size_t)(nb + nn) * 64 + l] = tile[l][nn];
}

// ---------------- kmeans init: copy0 of iter0 = first 4 points, cnt=1; zero rest
__global__ void kinit_k(const float* __restrict__ xmt, float* __restrict__ km){
  int t = threadIdx.x;
  km[t] = xmt[(size_t)(t >> 6) * 64 + (t & 63)];
  if (t < 4) km[256 + t] = 1.f;
  for (int j = 260 + t; j < 12 * ITST; j += 256) km[j] = 0.f;
}

// ---------------- kmeans assign + reduce (mode 0) or idx write (mode 1)
// kin/kout are 8 banked 260-float copies: load sums all 8; reduce adds to
// copy (blockIdx&7) -> same-address atomic chain depth 500 -> ~63.
__global__ __launch_bounds__(128) void assign_k(const float* __restrict__ xmt,
                                                const float* __restrict__ kin,
                                                float* __restrict__ kout,
                                                int* __restrict__ idx, int mode){
  __shared__ float s_cent[256];
  __shared__ float s_cc[4];
  __shared__ float s_red[260];
  __shared__ float s_x[128 * 65];
  __shared__ int   s_kb[128];
  int t = threadIdx.x, lane = t & 63, wv = t >> 6;
  for (int j = t; j < 256; j += 128){
    float sum = 0.f, cnt = 0.f;
#pragma unroll
    for (int s = 0; s < NCPY; s++){
      sum += kin[s * 260 + j];
      cnt += kin[s * 260 + 256 + (j >> 6)];
    }
    s_cent[j] = sum / fmaxf(cnt, 1.f);
  }
  for (int j = t; j < 260; j += 128) s_red[j] = 0.f;
  __syncthreads();
  if (t < 4){
    const float4* cc4 = (const float4*)(s_cent + t * 64);
    float s = 0.f;
#pragma unroll
    for (int q = 0; q < 16; q++){
      float4 v = cc4[q];
      s = fmaf(v.x, v.x, s); s = fmaf(v.y, v.y, s);
      s = fmaf(v.z, v.z, s); s = fmaf(v.w, v.w, s);
    }
    s_cc[t] = s;
  }
  __syncthreads();
  int n = blockIdx.x * 128 + t;
  const float4* xt = (const float4*)(xmt + (size_t)n * 64);
  float4 xq[16];
#pragma unroll
  for (int q = 0; q < 16; q++) xq[q] = xt[q];
  float d0 = 0.f, d1 = 0.f, d2 = 0.f, d3 = 0.f;
  const float4* c4 = (const float4*)s_cent;
#pragma unroll
  for (int q = 0; q < 16; q++){
    float4 p0 = c4[q], p1 = c4[16 + q], p2 = c4[32 + q], p3 = c4[48 + q];
    d0 = fmaf(p0.x, xq[q].x, d0); d0 = fmaf(p0.y, xq[q].y, d0);
    d0 = fmaf(p0.z, xq[q].z, d0); d0 = fmaf(p0.w, xq[q].w, d0);
    d1 = fmaf(p1.x, xq[q].x, d1); d1 = fmaf(p1.y, xq[q].y, d1);
    d1 = fmaf(p1.z, xq[q].z, d1); d1 = fmaf(p1.w, xq[q].w, d1);
    d2 = fmaf(p2.x, xq[q].x, d2); d2 = fmaf(p2.y, xq[q].y, d2);
    d2 = fmaf(p2.z, xq[q].z, d2); d2 = fmaf(p2.w, xq[q].w, d2);
    d3 = fmaf(p3.x, xq[q].x, d3); d3 = fmaf(p3.y, xq[q].y, d3);
    d3 = fmaf(p3.z, xq[q].z, d3); d3 = fmaf(p3.w, xq[q].w, d3);
  }
  float sc0 = s_cc[0] - 2.f * d0;
  float sc1 = s_cc[1] - 2.f * d1;
  float sc2 = s_cc[2] - 2.f * d2;
  float sc3 = s_cc[3] - 2.f * d3;
  int kb = 0; float bs = sc0;
  if (sc1 < bs){ bs = sc1; kb = 1; }
  if (sc2 < bs){ bs = sc2; kb = 2; }
  if (sc3 < bs){ bs = sc3; kb = 3; }
  if (mode){
    idx[n] = kb;
  } else {
    s_kb[t] = kb;
#pragma unroll
    for (int q = 0; q < 16; q++){
      s_x[t * 65 + 4*q + 0] = xq[q].x;
      s_x[t * 65 + 4*q + 1] = xq[q].y;
      s_x[t * 65 + 4*q + 2] = xq[q].z;
      s_x[t * 65 + 4*q + 3] = xq[q].w;
    }
    __syncthreads();
    float a0 = 0.f, a1 = 0.f, a2 = 0.f, a3 = 0.f;
    int rowbase = wv * 64;
#pragma unroll 16
    for (int j = 0; j < 64; j++){
      float v = s_x[(rowbase + j) * 65 + lane];
      int kj = s_kb[rowbase + j];
      a0 += (kj == 0) ? v : 0.f;
      a1 += (kj == 1) ? v : 0.f;
      a2 += (kj == 2) ? v : 0.f;
      a3 += (kj == 3) ? v : 0.f;
    }
    atomicAdd(&s_red[lane], a0);
    atomicAdd(&s_red[64 + lane], a1);
    atomicAdd(&s_red[128 + lane], a2);
    atomicAdd(&s_red[192 + lane], a3);
#pragma unroll
    for (int kk = 0; kk < 4; kk++){
      unsigned long long m = __ballot(kb == kk);
      if (lane == 0) atomicAdd(&s_red[256 + kk], (float)__popcll(m));
    }
    __syncthreads();
    float* kslot = kout + (blockIdx.x & (NCPY - 1)) * 260;
    for (int j = t; j < 260; j += 128) atomicAdd(&kslot[j], s_red[j]);
  }
}

// ---------------- gating MLPs (1 block, 256 thr); sums the 8 banked copies
__global__ void mlp_k(const float* __restrict__ km10,
                      const float* __restrict__ w1, const float* __restrict__ b1,
                      const float* __restrict__ w2, const float* __restrict__ b2,
                      const float* __restrict__ w3, const float* __restrict__ b3,
                      const float* __restrict__ u1, const float* __restrict__ c1,
                      const float* __restrict__ u2, const float* __restrict__ c2,
                      const float* __restrict__ u3, const float* __restrict__ c3,
                      float* __restrict__ wi, float* __restrict__ bias){
  __shared__ float s_feat[256], s_h1[128], s_h2[128], s_g1[64], s_g2[64];
  int t = threadIdx.x;
  {
    float sum = 0.f, cnt = 0.f;
#pragma unroll
    for (int s = 0; s < NCPY; s++){
      sum += km10[s * 260 + t];
      cnt += km10[s * 260 + 256 + (t >> 6)];
    }
    s_feat[t] = sum / fmaxf(cnt, 1.f);
  }
  __syncthreads();
  if (t < 128){
    float z = b1[t];
    for (int i = 0; i < 256; i++) z = fmaf(s_feat[i], w1[i * 128 + t], z);
    s_h1[t] = fmaxf(z, 0.f);
  }
  __syncthreads();
  if (t < 128){
    float z = b2[t];
    for (int i = 0; i < 128; i++) z = fmaf(s_h1[i], w2[i * 128 + t], z);
    s_h2[t] = fmaxf(z, 0.f);
  }
  __syncthreads();
  if (t < 108){
    float z = b3[t];
    for (int i = 0; i < 128; i++) z = fmaf(s_h2[i], w3[i * 108 + t], z);
    wi[t] = 1.f / (1.f + expf(-z));
  }
  if (t < 64){
    float z = c1[t];
    for (int i = 0; i < 256; i++) z = fmaf(s_feat[i], u1[i * 64 + t], z);
    s_g1[t] = fmaxf(z, 0.f);
  }
  __syncthreads();
  if (t < 64){
    float z = c2[t];
    for (int i = 0; i < 64; i++) z = fmaf(s_g1[i], u2[i * 64 + t], z);
    s_g2[t] = fmaxf(z, 0.f);
  }
  __syncthreads();
  {
    float z = c3[t];
    for (int i = 0; i < 64; i++) z = fmaf(s_g2[i], u3[i * 256 + t], z);
    bias[t] = z;
  }
}

// ---------------- base_w fp32 (o,c,t) -> bf16 [t][o][c]
__global__ void bwprep_k(const float* __restrict__ bw, short* __restrict__ bwb){
  int e = blockIdx.x * 256 + threadIdx.x;           // 0 .. 110591
  int t = e >> 12; int rem = e & 4095;
  int o = rem >> 6; int c = rem & 63;
  bwb[e] = (short)bf16rne(bw[(o * 64 + c) * 27 + t]);
}

// ---------------- main dynamic conv (R5-verbatim, passing at 49 us)
__global__ __launch_bounds__(256) void conv_k(const short* __restrict__ xpt,
                                              const short* __restrict__ bwb,
                                              const float* __restrict__ wi,
                                              const float* __restrict__ bias,
                                              const int* __restrict__ idx,
                                              const float* __restrict__ x,
                                              const float* __restrict__ pa,
                                              float* __restrict__ out){
  static const int POFF[27] = {
    -P2-42-1, -P2-42, -P2-42+1, -P2-1, -P2, -P2+1, -P2+42-1, -P2+42, -P2+42+1,
    -42-1, -42, -42+1, -1, 0, 1, 42-1, 42, 42+1,
    P2-42-1, P2-42, P2-42+1, P2-1, P2, P2+1, P2+42-1, P2+42, P2+42+1 };
  __shared__ float s_wi[108];
  __shared__ float s_bias[256];
  __shared__ float s_acc[64 * 68];
  int tid = threadIdx.x;
  for (int j = tid; j < 108; j += 256) s_wi[j] = wi[j];
  s_bias[tid] = bias[tid];
  __syncthreads();
  int wv = tid >> 6, lane = tid & 63;
  int kc = wv & 1, mh = wv >> 1;
  int col = lane & 15, kg = lane >> 4;
  int vb = blockIdx.x * 64;
  int p4[4], ki4[4];
#pragma unroll
  for (int nt = 0; nt < 4; nt++){
    int v = vb + nt * 16 + col;
    ki4[nt] = idx[v];
    int d = v / 1600; int r = v - d * 1600; int h = r / 40; int w = r - h * 40;
    p4[nt] = ((d + 1) * 42 + (h + 1)) * 42 + (w + 1);
  }
  const short* bg = xpt + (size_t)(kc * 4 + kg) * GSTR;
  const short* bp0 = bg + (size_t)p4[0] * 8;
  const short* bp1 = bg + (size_t)p4[1] * 8;
  const short* bp2 = bg + (size_t)p4[2] * 8;
  const short* bp3 = bg + (size_t)p4[3] * 8;
  int ao0 = (mh * 32 + col) * 64 + kc * 32 + kg * 8;
  int ao1 = ao0 + 16 * 64;
  v4f acc[2][4];
#pragma unroll
  for (int m2 = 0; m2 < 2; m2++)
#pragma unroll
    for (int nt = 0; nt < 4; nt++) acc[m2][nt] = (v4f){0.f, 0.f, 0.f, 0.f};
  v4f zero = {0.f, 0.f, 0.f, 0.f};
#pragma unroll 9
  for (int t = 0; t < 27; t++){
    int po8 = POFF[t] * 8;
    v8s a0 = *(const v8s*)(bwb + t * 4096 + ao0);
    v8s a1 = *(const v8s*)(bwb + t * 4096 + ao1);
    v8s b0 = *(const v8s*)(bp0 + po8);
    v8s b1 = *(const v8s*)(bp1 + po8);
    v8s b2 = *(const v8s*)(bp2 + po8);
    v8s b3 = *(const v8s*)(bp3 + po8);
    float wk0 = s_wi[ki4[0] * 27 + t];
    float wk1 = s_wi[ki4[1] * 27 + t];
    float wk2 = s_wi[ki4[2] * 27 + t];
    float wk3 = s_wi[ki4[3] * 27 + t];
    v4f tp;
    tp = __builtin_amdgcn_mfma_f32_16x16x32_bf16(a0, b0, zero, 0, 0, 0); acc[0][0] += tp * wk0;
    tp = __builtin_amdgcn_mfma_f32_16x16x32_bf16(a1, b0, zero, 0, 0, 0); acc[1][0] += tp * wk0;
    tp = __builtin_amdgcn_mfma_f32_16x16x32_bf16(a0, b1, zero, 0, 0, 0); acc[0][1] += tp * wk1;
    tp = __builtin_amdgcn_mfma_f32_16x16x32_bf16(a1, b1, zero, 0, 0, 0); acc[1][1] += tp * wk1;
    tp = __builtin_amdgcn_mfma_f32_16x16x32_bf16(a0, b2, zero, 0, 0, 0); acc[0][2] += tp * wk2;
    tp = __builtin_amdgcn_mfma_f32_16x16x32_bf16(a1, b2, zero, 0, 0, 0); acc[1][2] += tp * wk2;
    tp = __builtin_amdgcn_mfma_f32_16x16x32_bf16(a0, b3, zero, 0, 0, 0); acc[0][3] += tp * wk3;
    tp = __builtin_amdgcn_mfma_f32_16x16x32_bf16(a1, b3, zero, 0, 0, 0); acc[1][3] += tp * wk3;
  }
  __syncthreads();
  if (kc == 1){
#pragma unroll
    for (int m2 = 0; m2 < 2; m2++)
#pragma unroll
      for (int nt = 0; nt < 4; nt++)
        *(v4f*)(&s_acc[(nt * 16 + col) * 68 + mh * 32 + m2 * 16 + kg * 4]) = acc[m2][nt];
  }
  __syncthreads();
  if (kc == 0){
    float pav = pa[0];
#pragma unroll
    for (int m2 = 0; m2 < 2; m2++){
#pragma unroll
      for (int nt = 0; nt < 4; nt++){
        v4f other = *(const v4f*)(&s_acc[(nt * 16 + col) * 68 + mh * 32 + m2 * 16 + kg * 4]);
        v4f sum = acc[m2][nt] + other;
        int n = vb + nt * 16 + col;
#pragma unroll
        for (int r = 0; r < 4; r++){
          int o = mh * 32 + m2 * 16 + kg * 4 + r;
          float val = sum[r] + s_bias[ki4[nt] * 64 + o];
          val = (val >= 0.f) ? val : pav * val;
          size_t off = (size_t)o * NVOX + n;
          out[off] = val + x[off];
        }
      }
    }
  }
}

extern "C" void kernel_launch(void* const* d_in, const int* in_sizes, int n_in,
                              void* d_out, int out_size, void* d_ws, size_t ws_size,
                              hipStream_t stream){
  const float* x    = (const float*)d_in[0];
  const float* pw   = (const float*)d_in[1];
  const float* bw   = (const float*)d_in[2];
  const float* gkw1 = (const float*)d_in[3];
  const float* gkb1 = (const float*)d_in[4];
  const float* gkw2 = (const float*)d_in[5];
  const float* gkb2 = (const float*)d_in[6];
  const float* gkw3 = (const float*)d_in[7];
  const float* gkb3 = (const float*)d_in[8];
  const float* gbw1 = (const float*)d_in[9];
  const float* gbb1 = (const float*)d_in[10];
  const float* gbw2 = (const float*)d_in[11];
  const float* gbb2 = (const float*)d_in[12];
  const float* gbw3 = (const float*)d_in[13];
  const float* gbb3 = (const float*)d_in[14];
  const float* pa   = (const float*)d_in[15];
  float* outp = (float*)d_out;

  float* ws   = (float*)d_ws;
  float* XP   = ws;                                  // 4,096,000 f ; reused as XMT
  float* BU2  = ws + 4096000;                        // 4,096,000 f
  float* BU1  = ws + 8192000;                        // 4,096,000 f (xm [c][n])
  short* XPT  = (short*)(ws + 12288000);             // 4,741,632 s
  short* BWB  = XPT + (size_t)NPAD * 64;             // 110,592 s
  float* KM   = (float*)(BWB + 110592);              // 12*2080 f
  float* WI   = KM + 12 * ITST;                      // 108 f
  float* BIAS = WI + 108;                            // 256 f
  int*   IDX  = (int*)(BIAS + 256);                  // 64,000 i
  float* XMT  = XP;                                  // xm transposed [n][c]

  hipMemsetAsync(XPT, 0, (size_t)NPAD * 64 * 2, stream);
  proj_k<<<500, 256, 0, stream>>>(x, pw, XP, XPT);
  boxwh_k<<<2560, 256, 0, stream>>>(XP, BU2);
  boxd_k<<<16000, 256, 0, stream>>>(BU2, BU1);
  transp_k<<<1000, 256, 0, stream>>>(BU1, XMT);
  kinit_k<<<1, 256, 0, stream>>>(XMT, KM);
  for (int i = 0; i <= 10; i++)
    assign_k<<<500, 128, 0, stream>>>(XMT, KM + i * ITST, KM + (i + 1) * ITST, IDX,
                                      (i == 10) ? 1 : 0);
  mlp_k<<<1, 256, 0, stream>>>(KM + 10 * ITST,
                               gkw1, gkb1, gkw2, gkb2, gkw3, gkb3,
                               gbw1, gbb1, gbw2, gbb2, gbw3, gbb3,
                               WI, BIAS);
  bwprep_k<<<432, 256, 0, stream>>>(bw, BWB);
  conv_k<<<1000, 256, 0, stream>>>(XPT, BWB, WI, BIAS, IDX, x, pa, outp);
}